// Round 1
// 2252.400 us; speedup vs baseline: 1.1731x; 1.1731x over previous
//
#include <hip/hip_runtime.h>

#define NB 64
#define NS 2048
#define ND 2048
#define NH 16
#define PAD_ID 50257
#define LN_EPS 1e-5f

// ---------------------------------------------------------------------------
// Single-query GPT-Neo head attention, algebraically restructured:
//   never materialize K, V, or h_norm.  Two streaming passes over the 1 GiB
//   hidden_states (score pass, weighted-sum pass); everything else is small.
//
// R1 change: passA/passB block-uniform operands (ug / coef) used to be read
//   via s_load_dwordx4 inside the inner loop.  SMEM completes out-of-order ->
//   every use forces s_waitcnt lgkmcnt(0), draining the ds_read pipeline too
//   (VALUBusy 52%, HBM 8.5% of peak).  Both operands are now staged into LDS
//   per chunk so the inner loop is ds_read-only on lgkmcnt (partial counts,
//   pipelinable) + global/vmcnt.
// ---------------------------------------------------------------------------

__device__ __forceinline__ float wave_reduce_sum(float v){
#pragma unroll
  for (int off = 32; off; off >>= 1) v += __shfl_xor(v, off);
  return v;
}
__device__ __forceinline__ float wave_reduce_max(float v){
#pragma unroll
  for (int off = 32; off; off >>= 1) v = fmaxf(v, __shfl_xor(v, off));
  return v;
}

// --- last non-pad token index per batch row (argmax of cumsum == last non-pad, 0 if all pad)
__global__ __launch_bounds__(256) void k_sel(const int* __restrict__ ids, int* __restrict__ sel){
  __shared__ int red[256];
  int b = blockIdx.x;
  int loc = -1;
  for (int s = threadIdx.x; s < NS; s += 256){
    if (ids[b*NS + s] != PAD_ID) loc = s;   // increasing s -> keeps max
  }
  red[threadIdx.x] = loc;
  __syncthreads();
  for (int off = 128; off; off >>= 1){
    if (threadIdx.x < (unsigned)off) red[threadIdx.x] = max(red[threadIdx.x], red[threadIdx.x+off]);
    __syncthreads();
  }
  if (threadIdx.x == 0) sel[b] = red[0] < 0 ? 0 : red[0];
}

// --- LayerNorm the selected row, write TRANSPOSED [d][b] for the q-projection GEMM
__global__ __launch_bounds__(256) void k_hlast(const float* __restrict__ X, const int* __restrict__ sel,
    const float* __restrict__ gamma, const float* __restrict__ beta, float* __restrict__ hlastT){
  __shared__ float red[8];
  __shared__ float s_stats[2];
  int b = blockIdx.x;
  const float* row = X + ((size_t)b*NS + sel[b]) * ND;
  int tid = threadIdx.x;
  float sum = 0.f, sq = 0.f;
  for (int d = tid; d < ND; d += 256){ float x = row[d]; sum += x; sq += x*x; }
  sum = wave_reduce_sum(sum); sq = wave_reduce_sum(sq);
  int lane = tid & 63, wv = tid >> 6;
  if (lane == 0){ red[wv] = sum; red[4+wv] = sq; }
  __syncthreads();
  if (tid == 0){
    float ts = red[0]+red[1]+red[2]+red[3];
    float tq = red[4]+red[5]+red[6]+red[7];
    float mu = ts * (1.f/ND);
    float var = tq * (1.f/ND) - mu*mu;
    s_stats[0] = mu; s_stats[1] = rsqrtf(var + LN_EPS);
  }
  __syncthreads();
  float mu = s_stats[0], rs = s_stats[1];
  for (int d = tid; d < ND; d += 256)
    hlastT[d*NB + b] = (row[d]-mu)*rs*gamma[d] + beta[d];   // scattered but tiny (512 KB)
}

// --- zero the atomically-accumulated buffers (ws is poisoned 0xAA each launch)
__global__ __launch_bounds__(256) void k_init(float* __restrict__ qT, float* __restrict__ ctxT,
                                              float* __restrict__ outT){
  int i = blockIdx.x*256 + threadIdx.x;   // grid 512 -> 131072 = ND*NB
  qT[i] = 0.f; ctxT[i] = 0.f; outT[i] = 0.f;
}

// --- generic small GEMM:  YT[i][b] += sum_k W[i][k] * XT[k][b]
//     lane = b (wave=64=B!), W goes through the scalar path (wave-uniform address),
//     XT loads coalesced.  k-split 16 with fp32 atomics.
__global__ __launch_bounds__(256) void k_gemmT(const float* __restrict__ XT, long xoffz,
    const float* __restrict__ W, int ibz, float* __restrict__ YT){
  int h    = blockIdx.z;
  int lane = threadIdx.x & 63;
  int wv   = __builtin_amdgcn_readfirstlane(threadIdx.x >> 6);
  int i0   = h*ibz + blockIdx.x*64 + wv*16;   // wave owns 16 output columns
  int k0   = blockIdx.y * 128;                // ksplit 16
  const float* xt = XT + (size_t)h*xoffz + (size_t)k0*NB + lane;
  float acc[16];
#pragma unroll
  for (int ii = 0; ii < 16; ++ii) acc[ii] = 0.f;
#pragma unroll 4
  for (int kk = 0; kk < 128; ++kk){
    float xv = xt[(size_t)kk*NB];                           // coalesced vector load
#pragma unroll
    for (int ii = 0; ii < 16; ++ii)
      acc[ii] += W[(size_t)(i0+ii)*ND + k0 + kk] * xv;      // uniform -> s_load
  }
#pragma unroll
  for (int ii = 0; ii < 16; ++ii)
    atomicAdd(&YT[(size_t)(i0+ii)*NB + lane], acc[ii]);     // coalesced atomics
}

// --- u[b,h,:] = gamma ⊙ (Wk_h^T q[b,h]);  lanes over d (coalesced Wk), q via scalar path
__global__ __launch_bounds__(256) void k_ucalc(const float* __restrict__ qT, const float* __restrict__ Wk,
    const float* __restrict__ gamma, float* __restrict__ ug){
  int h  = blockIdx.x;                       // 16
  int d  = blockIdx.y*256 + threadIdx.x;     // 8 x 256
  int b0 = blockIdx.z * 16;                  // 4
  float acc[16];
#pragma unroll
  for (int bb = 0; bb < 16; ++bb) acc[bb] = 0.f;
  const float* wkp = Wk + (size_t)(h*128)*ND + d;
  const float* qp  = qT + (size_t)(h*128)*NB + b0;
#pragma unroll 2
  for (int j = 0; j < 128; ++j){
    float wk = wkp[(size_t)j*ND];            // coalesced
#pragma unroll
    for (int bb = 0; bb < 16; ++bb) acc[bb] += qp[j*NB + bb] * wk;   // uniform -> s_load
  }
  float g = gamma[d];
#pragma unroll
  for (int bb = 0; bb < 16; ++bb)
    ug[((size_t)((b0+bb)*NH + h))*ND + d] = g * acc[bb];
}

// --- C1[b,h] = sum_d ug[b,h,d]   (the mu-coupling constant; beta term is softmax-invariant)
__global__ __launch_bounds__(256) void k_c1(const float* __restrict__ ug, float* __restrict__ C1){
  __shared__ float red[4];
  int bh = blockIdx.x;
  const float* p = ug + (size_t)bh*ND;
  float s = 0.f;
  for (int d = threadIdx.x; d < ND; d += 256) s += p[d];
  s = wave_reduce_sum(s);
  int lane = threadIdx.x & 63, wv = threadIdx.x >> 6;
  if (lane == 0) red[wv] = s;
  __syncthreads();
  if (threadIdx.x == 0) C1[bh] = red[0]+red[1]+red[2]+red[3];
}

// --- PASS A: one streaming read of hidden_states.
//     Per row s: mu, rstd, and 16 dots with ug -> scores.
//     x-tile transposed through LDS (stride-65, conflict-free) so each THREAD owns one
//     s-row.  ug chunk is ALSO staged in LDS (broadcast reads, conflict-free) so the
//     inner loop has no SMEM ops -> partial lgkmcnt counts, compiler can pipeline.
__global__ __launch_bounds__(128, 2) void k_passA(const float* __restrict__ X, const float* __restrict__ ug,
    const float* __restrict__ C1, float* __restrict__ sbuf, float* __restrict__ mubuf,
    float* __restrict__ rsbuf){
  __shared__ __align__(16) float xs[128*65];     // 33.3 KB
  __shared__ __align__(16) float us[16*64];      // 4 KB ug chunk: us[h][d']
  int b  = blockIdx.y;
  int s0 = blockIdx.x * 128;
  int tid = threadIdx.x;                     // thread owns row s0+tid
  const float* xb  = X  + ((size_t)b*NS + s0) * ND;
  const float* ugb = ug + (size_t)b*NH*ND;
  float accd[16]; float acs = 0.f, acs2 = 0.f;
#pragma unroll
  for (int h = 0; h < 16; ++h) accd[h] = 0.f;

  for (int c = 0; c < 32; ++c){              // 32 chunks of 64 d
    int d0 = c*64;
    __syncthreads();
#pragma unroll
    for (int it = 0; it < 16; ++it){         // stage 128 rows x 64 d, transposed
      int e  = it*128 + tid;                 // 0..2047 float4 units
      int r  = e >> 4;
      int f4 = (e & 15) << 2;
      const float4 xv = *(const float4*)(xb + (size_t)r*ND + d0 + f4);
      float* w = xs + r*65 + f4;
      w[0] = xv.x; w[1] = xv.y; w[2] = xv.z; w[3] = xv.w;
    }
#pragma unroll
    for (int it = 0; it < 8; ++it){          // stage ug chunk: 16 h x 64 d
      int e = it*128 + tid;                  // 0..1023
      us[e] = ugb[(size_t)(e >> 6)*ND + d0 + (e & 63)];
    }
    __syncthreads();
#pragma unroll 4
    for (int dq = 0; dq < 16; ++dq){
      float x0 = xs[tid*65 + dq*4 + 0];
      float x1 = xs[tid*65 + dq*4 + 1];
      float x2 = xs[tid*65 + dq*4 + 2];
      float x3 = xs[tid*65 + dq*4 + 3];
      acs  += (x0+x1) + (x2+x3);
      acs2 += x0*x0 + x1*x1 + x2*x2 + x3*x3;
#pragma unroll
      for (int hh = 0; hh < 16; ++hh){
        const float4 u4 = *(const float4*)(us + hh*64 + dq*4);   // LDS broadcast, conflict-free
        accd[hh] += x0*u4.x + x1*u4.y + x2*u4.z + x3*u4.w;
      }
    }
  }
  int s = s0 + tid;
  float mu  = acs  * (1.f/ND);
  float var = acs2 * (1.f/ND) - mu*mu;
  float rs  = rsqrtf(var + LN_EPS);
  mubuf[b*NS + s] = mu;
  rsbuf[b*NS + s] = rs;
#pragma unroll
  for (int hh = 0; hh < 16; ++hh)
    sbuf[((size_t)(b*NH+hh))*NS + s] = rs * (accd[hh] - mu * C1[b*NH+hh]);  // coalesced
}

// --- softmax per (b,h); in-place scores -> coef = attn*rstd; M[b,h] = sum attn*rstd*mu
__global__ __launch_bounds__(256) void k_softmax(float* __restrict__ sbuf, const float* __restrict__ mubuf,
    const float* __restrict__ rsbuf, float* __restrict__ Mbuf){
  __shared__ float red[12];
  int bh = blockIdx.x; int b = bh >> 4;
  float* row = sbuf + (size_t)bh*NS;
  const float* mup = mubuf + b*NS;
  const float* rsp = rsbuf + b*NS;
  int tid = threadIdx.x, lane = tid & 63, wv = tid >> 6;
  float v[8]; float m = -1e30f;
#pragma unroll
  for (int i = 0; i < 8; ++i){ v[i] = row[tid + i*256]; m = fmaxf(m, v[i]); }
  m = wave_reduce_max(m);
  if (lane == 0) red[wv] = m;
  __syncthreads();
  m = fmaxf(fmaxf(red[0],red[1]), fmaxf(red[2],red[3]));
  float p[8], sum = 0.f, ms = 0.f;
#pragma unroll
  for (int i = 0; i < 8; ++i){
    int s = tid + i*256;
    float e = __expf(v[i] - m);
    float r = rsp[s];
    sum += e;
    ms  += e * r * mup[s];
    p[i] = e * r;
  }
  sum = wave_reduce_sum(sum); ms = wave_reduce_sum(ms);
  if (lane == 0){ red[4+wv] = sum; red[8+wv] = ms; }
  __syncthreads();
  sum = red[4]+red[5]+red[6]+red[7];
  ms  = red[8]+red[9]+red[10]+red[11];
  float inv = 1.f/sum;
#pragma unroll
  for (int i = 0; i < 8; ++i) row[tid + i*256] = p[i]*inv;
  if (tid == 0) Mbuf[bh] = ms*inv;
}

// --- PASS B: second streaming read of hidden_states.
//     w[b,h,d] = gamma_d*( sum_s coef[b,h,s]*x[b,s,d]  -  M[b,h] ) + beta_d
//     lanes over d (coalesced x); coef chunk staged in LDS (broadcast reads) so
//     the FMA operands never touch SMEM/lgkmcnt(0) drains.
__global__ __launch_bounds__(256) void k_passB(const float* __restrict__ X, const float* __restrict__ cf0,
    const float* __restrict__ Mbuf, const float* __restrict__ gamma, const float* __restrict__ beta,
    float* __restrict__ w){
  __shared__ __align__(16) float cs[16*128];   // 8 KB coef chunk: cs[h][s']
  int b = blockIdx.y;
  int d = blockIdx.x*256 + threadIdx.x;
  int tid = threadIdx.x;
  const float* xb = X   + (size_t)b*NS*ND + d;
  const float* cf = cf0 + (size_t)b*NH*NS;
  float acc[16];
#pragma unroll
  for (int h = 0; h < 16; ++h) acc[h] = 0.f;
  for (int sc = 0; sc < NS/128; ++sc){         // 16 chunks of 128 s
    int s0 = sc*128;
    __syncthreads();
#pragma unroll
    for (int it = 0; it < 8; ++it){            // stage 16 h x 128 s coef
      int e = it*256 + tid;                    // 0..2047
      cs[e] = cf[(size_t)(e >> 7)*NS + s0 + (e & 127)];
    }
    __syncthreads();
#pragma unroll 2
    for (int s4 = 0; s4 < 32; ++s4){
      float x0 = xb[(size_t)(s0 + s4*4 + 0)*ND];
      float x1 = xb[(size_t)(s0 + s4*4 + 1)*ND];
      float x2 = xb[(size_t)(s0 + s4*4 + 2)*ND];
      float x3 = xb[(size_t)(s0 + s4*4 + 3)*ND];
#pragma unroll
      for (int h = 0; h < 16; ++h){
        const float4 c4 = *(const float4*)(cs + h*128 + s4*4);   // LDS broadcast
        acc[h] += x0*c4.x + x1*c4.y + x2*c4.z + x3*c4.w;
      }
    }
  }
  float g = gamma[d], be = beta[d];
#pragma unroll
  for (int h = 0; h < 16; ++h)
    w[((size_t)(b*NH+h))*ND + d] = g * (acc[h] - Mbuf[b*NH+h]) + be;
}

// --- transpose w [b,h,d] -> wT [(h,d)][b] via LDS tiles (for the ctx-projection GEMM)
__global__ __launch_bounds__(256) void k_wT(const float* __restrict__ w, float* __restrict__ wT){
  __shared__ float t[64*65];
  int d0 = blockIdx.x * 64;   // 32
  int h  = blockIdx.y;        // 16
  int tid = threadIdx.x;
#pragma unroll
  for (int it = 0; it < 16; ++it){
    int e  = it*256 + tid;    // 0..4095
    int br = e >> 6;
    int dl = e & 63;
    t[dl*65 + br] = w[((size_t)(br*NH + h))*ND + d0 + dl];   // coalesced read
  }
  __syncthreads();
#pragma unroll
  for (int it = 0; it < 16; ++it){
    int e  = it*256 + tid;
    int dl = e >> 6;
    int br = e & 63;
    wT[((size_t)(h*ND + d0 + dl))*NB + br] = t[dl*65 + br];  // coalesced write
  }
}

// --- final: out[b][i] = outT[i][b] + bo[i]  (LDS transpose)
__global__ __launch_bounds__(256) void k_out(const float* __restrict__ outT, const float* __restrict__ bo,
                                             float* __restrict__ out){
  __shared__ float t[64*65];
  int i0 = blockIdx.x * 64;   // 32
  int tid = threadIdx.x;
#pragma unroll
  for (int it = 0; it < 16; ++it){
    int e  = it*256 + tid;
    int il = e >> 6;
    int br = e & 63;
    t[il*65 + br] = outT[(size_t)(i0+il)*NB + br];
  }
  __syncthreads();
#pragma unroll
  for (int it = 0; it < 16; ++it){
    int e  = it*256 + tid;
    int br = e >> 6;
    int il = e & 63;
    out[(size_t)br*ND + i0 + il] = t[il*65 + br] + bo[i0 + il];
  }
}

extern "C" void kernel_launch(void* const* d_in, const int* in_sizes, int n_in,
                              void* d_out, int out_size, void* d_ws, size_t ws_size,
                              hipStream_t stream){
  const float* X     = (const float*)d_in[0];
  const int*   ids   = (const int*)  d_in[1];
  const float* gamma = (const float*)d_in[2];
  const float* beta  = (const float*)d_in[3];
  const float* Wq    = (const float*)d_in[4];
  const float* Wk    = (const float*)d_in[5];
  const float* Wv    = (const float*)d_in[6];
  const float* Wo    = (const float*)d_in[7];
  const float* bo    = (const float*)d_in[8];
  float* out = (float*)d_out;

  char* ws = (char*)d_ws;
  size_t off = 0;
  auto alloc = [&](size_t bytes)->char*{
    char* p = ws + off; off += (bytes + 255) & ~(size_t)255; return p;
  };
  int*   sel    = (int*)  alloc((size_t)NB*4);
  float* hlastT = (float*)alloc((size_t)ND*NB*4);
  float* qT     = (float*)alloc((size_t)ND*NB*4);
  float* ug     = (float*)alloc((size_t)NB*NH*ND*4);
  float* C1     = (float*)alloc((size_t)NB*NH*4);
  float* sbuf   = (float*)alloc((size_t)NB*NH*NS*4);
  float* mubuf  = (float*)alloc((size_t)NB*NS*4);
  float* rsbuf  = (float*)alloc((size_t)NB*NS*4);
  float* Mbuf   = (float*)alloc((size_t)NB*NH*4);
  float* wbuf   = (float*)alloc((size_t)NB*NH*ND*4);
  float* wT     = (float*)alloc((size_t)NH*ND*NB*4);
  float* ctxT   = (float*)alloc((size_t)ND*NB*4);
  float* outT   = (float*)alloc((size_t)ND*NB*4);
  (void)in_sizes; (void)n_in; (void)out_size; (void)ws_size;

  k_sel    <<<NB, 256, 0, stream>>>(ids, sel);
  k_hlast  <<<NB, 256, 0, stream>>>(X, sel, gamma, beta, hlastT);
  k_init   <<<512, 256, 0, stream>>>(qT, ctxT, outT);
  // q = hlast @ Wq^T        (qT[i][b])
  k_gemmT  <<<dim3(32,16,1), 256, 0, stream>>>(hlastT, 0, Wq, 0, qT);
  k_ucalc  <<<dim3(16,8,4), 256, 0, stream>>>(qT, Wk, gamma, ug);
  k_c1     <<<NB*NH, 256, 0, stream>>>(ug, C1);
  // score pass (reads hidden_states once)
  k_passA  <<<dim3(16,64), 128, 0, stream>>>(X, ug, C1, sbuf, mubuf, rsbuf);
  k_softmax<<<NB*NH, 256, 0, stream>>>(sbuf, mubuf, rsbuf, Mbuf);
  // weighted-sum pass (reads hidden_states once)
  k_passB  <<<dim3(8,64), 256, 0, stream>>>(X, sbuf, Mbuf, gamma, beta, wbuf);
  k_wT     <<<dim3(32,16), 256, 0, stream>>>(wbuf, wT);
  // ctx[b, h*128+j] = Wv_h @ w[b,h,:]   (per-head GEMM, ctxT[c][b])
  k_gemmT  <<<dim3(2,16,16), 256, 0, stream>>>(wT, (long)ND*NB, Wv, 128, ctxT);
  // out = ctx @ Wo^T   (outT[i][b])
  k_gemmT  <<<dim3(32,16,1), 256, 0, stream>>>(ctxT, 0, Wo, 0, outT);
  k_out    <<<32, 256, 0, stream>>>(outT, bo, out);
}